// Round 1
// baseline (1382.434 us; speedup 1.0000x reference)
//
#include <hip/hip_runtime.h>

#define PP   512
#define CC   32
#define HWD  3072           // 64*48
#define PDIMK 34
#define NIMG 32

static constexpr float INV_NORM  = 1.0f / 96.0f;
static constexpr float INV_PNORM = 1.0f / 480.0f;

// workspace int layout:
// [0..32]      gstart (33)
// [33]         npairs
// [64..575]    start[i]
// [576..1087]  cnt[i]
// [1088..1599] pairBase[i]  (exclusive prefix sum of cnt)
// byte 8192+:  rel/att buffer, [pair][CC] floats

__global__ void k_groups(const int* __restrict__ imgid, int* __restrict__ wsI) {
    __shared__ int s_img[PP];
    __shared__ int s_cnt[PP];
    int t = threadIdx.x;
    s_img[t] = imgid[t];
    __syncthreads();
    int v = s_img[t];
    int lo = 0, hi = PP;
    while (lo < hi) { int mid = (lo + hi) >> 1; if (s_img[mid] < v) lo = mid + 1; else hi = mid; }
    int st = lo;
    lo = 0; hi = PP;
    while (lo < hi) { int mid = (lo + hi) >> 1; if (s_img[mid] <= v) lo = mid + 1; else hi = mid; }
    int cn = lo - st;
    wsI[64 + t]  = st;
    wsI[576 + t] = cn;
    s_cnt[t] = cn;
    if (t <= NIMG) {  // gstart[m] = lower_bound(imgid, m)
        lo = 0; hi = PP;
        while (lo < hi) { int mid = (lo + hi) >> 1; if (s_img[mid] < t) lo = mid + 1; else hi = mid; }
        wsI[t] = lo;
    }
    __syncthreads();
    if (t == 0) {
        int acc = 0;
        for (int i = 0; i < PP; ++i) { wsI[1088 + i] = acc; acc += s_cnt[i]; }
        wsI[33] = acc;
    }
}

#define BT 64
#define DT 32

// Per-(image, channel) group Gram matrix: rel[c, i, j] = dot(x[c,i,:], x[c,j,:]) / 96
__global__ __launch_bounds__(256) void k_rel(const float* __restrict__ feats,
                                             const int* __restrict__ wsI,
                                             float* __restrict__ relbuf,
                                             int pairCap) {
    int m = blockIdx.x, c = blockIdx.y;
    int g0 = wsI[m], g1 = wsI[m + 1];
    int n = g1 - g0;
    if (n <= 0) return;
    const int* pairBase = wsI + 1088;
    __shared__ float Xi[BT][DT + 1];
    __shared__ float Xj[BT][DT + 1];
    int t = threadIdx.x;
    int tr = t >> 4, tc = t & 15;   // 16x16 thread grid, 4x4 accum each
    for (int it = 0; it < n; it += BT) {
        int ni = min(BT, n - it);
        for (int jt = 0; jt < n; jt += BT) {
            int nj = min(BT, n - jt);
            float acc[4][4] = {};
            for (int d0 = 0; d0 < HWD; d0 += DT) {
                __syncthreads();
                int col = t & 31;
                for (int r = t >> 5; r < BT; r += 8) {
                    float vi = 0.f, vj = 0.f;
                    if (r < ni) vi = feats[((size_t)(g0 + it + r) * CC + c) * HWD + d0 + col];
                    if (r < nj) vj = feats[((size_t)(g0 + jt + r) * CC + c) * HWD + d0 + col];
                    Xi[r][col] = vi;
                    Xj[r][col] = vj;
                }
                __syncthreads();
#pragma unroll
                for (int kk = 0; kk < DT; ++kk) {
                    float a0 = Xi[tr * 4 + 0][kk], a1 = Xi[tr * 4 + 1][kk];
                    float a2 = Xi[tr * 4 + 2][kk], a3 = Xi[tr * 4 + 3][kk];
                    float b0 = Xj[tc * 4 + 0][kk], b1 = Xj[tc * 4 + 1][kk];
                    float b2 = Xj[tc * 4 + 2][kk], b3 = Xj[tc * 4 + 3][kk];
                    acc[0][0] += a0 * b0; acc[0][1] += a0 * b1; acc[0][2] += a0 * b2; acc[0][3] += a0 * b3;
                    acc[1][0] += a1 * b0; acc[1][1] += a1 * b1; acc[1][2] += a1 * b2; acc[1][3] += a1 * b3;
                    acc[2][0] += a2 * b0; acc[2][1] += a2 * b1; acc[2][2] += a2 * b2; acc[2][3] += a2 * b3;
                    acc[3][0] += a3 * b0; acc[3][1] += a3 * b1; acc[3][2] += a3 * b2; acc[3][3] += a3 * b3;
                }
            }
#pragma unroll
            for (int a = 0; a < 4; ++a)
#pragma unroll
                for (int b = 0; b < 4; ++b) {
                    int ii = it + tr * 4 + a, jj = jt + tc * 4 + b;
                    if (ii < n && jj < n) {
                        long p = (long)pairBase[g0 + ii] + jj;
                        if (p < pairCap)
                            relbuf[p * CC + c] = acc[a][b] * INV_NORM;
                    }
                }
        }
    }
}

// Per-pair: add param term, softmax over 32 channels (in place)
__global__ void k_softmax(float* __restrict__ relbuf, const float* __restrict__ param,
                          const int* __restrict__ wsI, int pairCap) {
    int np = wsI[33];
    if (np > pairCap) np = pairCap;
    int p = blockIdx.x * blockDim.x + threadIdx.x;
    if (p >= np) return;
    const int* pairBase = wsI + 1088;
    int lo = 0, hi = PP - 1;   // largest i with pairBase[i] <= p
    while (lo < hi) { int mid = (lo + hi + 1) >> 1; if (pairBase[mid] <= p) lo = mid; else hi = mid - 1; }
    int i = lo;
    int j = wsI[64 + i] + (p - pairBase[i]);
    float pd = 0.f;
#pragma unroll
    for (int k = 0; k < PDIMK; ++k) pd += param[i * PDIMK + k] * param[j * PDIMK + k];
    pd *= INV_PNORM;
    float r[CC];
    float mx = -3.4e38f;
#pragma unroll
    for (int cq = 0; cq < CC; ++cq) { r[cq] = relbuf[(size_t)p * CC + cq] + pd; mx = fmaxf(mx, r[cq]); }
    float s = 0.f;
#pragma unroll
    for (int cq = 0; cq < CC; ++cq) { r[cq] = expf(r[cq] - mx); s += r[cq]; }
    float inv = 1.0f / s;
#pragma unroll
    for (int cq = 0; cq < CC; ++cq) relbuf[(size_t)p * CC + cq] = r[cq] * inv;
}

// out[i,c,d] = relu( sum_j att[c,i,j] * x[c,j,d] + x[c,i,d] )
__global__ __launch_bounds__(256) void k_out(const float* __restrict__ feats,
                                             const float* __restrict__ att,
                                             const int* __restrict__ wsI,
                                             float* __restrict__ out, int pairCap) {
    int m = blockIdx.x, c = blockIdx.y;
    int g0 = wsI[m], n = wsI[m + 1] - g0;
    if (n <= 0) return;
    const int* pairBase = wsI + 1088;
    int t = threadIdx.x;
    if (n <= 64) {
        __shared__ float att_s[64][64];
        __shared__ float Xs[64][256];
        for (int idx = t; idx < n * n; idx += 256) {
            int ii = idx / n, jj = idx - ii * n;
            long p = (long)pairBase[g0 + ii] + jj;
            att_s[ii][jj] = (p < pairCap) ? att[p * CC + c] : 0.f;
        }
        for (int d0 = 0; d0 < HWD; d0 += 256) {
            __syncthreads();
            for (int r = 0; r < n; ++r)
                Xs[r][t] = feats[((size_t)(g0 + r) * CC + c) * HWD + d0 + t];
            __syncthreads();
            for (int ii = 0; ii < n; ++ii) {
                float acc = 0.f;
                for (int jj = 0; jj < n; ++jj)
                    acc += att_s[ii][jj] * Xs[jj][t];
                out[((size_t)(g0 + ii) * CC + c) * HWD + d0 + t] = fmaxf(acc + Xs[ii][t], 0.f);
            }
        }
    } else {
        // general fallback (statistically unreachable for this data): direct global reads
        for (int d0 = 0; d0 < HWD; d0 += 256) {
            int d = d0 + t;
            for (int ii = 0; ii < n; ++ii) {
                long pb = pairBase[g0 + ii];
                float acc = 0.f;
                for (int jj = 0; jj < n; ++jj) {
                    float a = (pb + jj < pairCap) ? att[(pb + jj) * CC + c] : 0.f;
                    acc += a * feats[((size_t)(g0 + jj) * CC + c) * HWD + d];
                }
                float x0 = feats[((size_t)(g0 + ii) * CC + c) * HWD + d];
                out[((size_t)(g0 + ii) * CC + c) * HWD + d] = fmaxf(acc + x0, 0.f);
            }
        }
    }
}

extern "C" void kernel_launch(void* const* d_in, const int* in_sizes, int n_in,
                              void* d_out, int out_size, void* d_ws, size_t ws_size,
                              hipStream_t stream) {
    const float* feats = (const float*)d_in[0];
    const int*   imgid = (const int*)d_in[1];
    const float* param = (const float*)d_in[2];
    float* out = (float*)d_out;
    int* wsI = (int*)d_ws;
    float* relbuf = (float*)((char*)d_ws + 8192);

    long pairCapL = ((long)ws_size - 8192) / (CC * 4);
    if (pairCapL < 0) pairCapL = 0;
    if (pairCapL > (long)PP * PP) pairCapL = (long)PP * PP;
    int pairCap = (int)pairCapL;

    k_groups<<<1, PP, 0, stream>>>(imgid, wsI);
    k_rel<<<dim3(NIMG, CC), 256, 0, stream>>>(feats, wsI, relbuf, pairCap);
    k_softmax<<<dim3((PP * PP + 255) / 256), 256, 0, stream>>>(relbuf, param, wsI, pairCap);
    k_out<<<dim3(NIMG, CC), 256, 0, stream>>>(feats, relbuf, wsI, out, pairCap);
}

// Round 2
// 464.715 us; speedup vs baseline: 2.9748x; 2.9748x over previous
//
#include <hip/hip_runtime.h>

#define PP   512
#define CC   32
#define HWD  3072           // 64*48
#define PDIMK 34
#define NIMG 32
#define DT   64

static constexpr float INV_NORM  = 1.0f / 96.0f;
static constexpr float INV_PNORM = 1.0f / 480.0f;

// workspace int layout:
// [0..32]      gstart (33)
// [33]         npairs
// [64..575]    start[i]
// [576..1087]  cnt[i]
// [1088..1599] pairBase[i]  (exclusive prefix sum of cnt)
// byte 8192+:  rel/att buffer, [pair][CC] floats

__global__ void k_groups(const int* __restrict__ imgid, int* __restrict__ wsI) {
    __shared__ int s_img[PP];
    __shared__ int s_cnt[PP];
    int t = threadIdx.x;
    s_img[t] = imgid[t];
    __syncthreads();
    int v = s_img[t];
    int lo = 0, hi = PP;
    while (lo < hi) { int mid = (lo + hi) >> 1; if (s_img[mid] < v) lo = mid + 1; else hi = mid; }
    int st = lo;
    lo = 0; hi = PP;
    while (lo < hi) { int mid = (lo + hi) >> 1; if (s_img[mid] <= v) lo = mid + 1; else hi = mid; }
    int cn = lo - st;
    wsI[64 + t]  = st;
    wsI[576 + t] = cn;
    s_cnt[t] = cn;
    if (t <= NIMG) {  // gstart[m] = lower_bound(imgid, m)
        lo = 0; hi = PP;
        while (lo < hi) { int mid = (lo + hi) >> 1; if (s_img[mid] < t) lo = mid + 1; else hi = mid; }
        wsI[t] = lo;
    }
    __syncthreads();
    if (t == 0) {
        int acc = 0;
        for (int i = 0; i < PP; ++i) { wsI[1088 + i] = acc; acc += s_cnt[i]; }
        wsI[33] = acc;
    }
}

// Per-(image, channel) group Gram: rel[c,i,j] = dot(x[c,i,:], x[c,j,:]) / 96
// Adaptive register tile R: 16R x 16R coverage per (it,jt) tile; R chosen so a
// typical group (n~16) computes EXACTLY its pairs (R=1), no padded waste.
template<int R>
__device__ __forceinline__ void rel_impl(const float* __restrict__ feats,
                                         const int* __restrict__ pairBase,
                                         float* __restrict__ relbuf, int pairCap,
                                         int c, int g0, int n,
                                         float (*Xi)[DT + 4], float (*Xj)[DT + 4]) {
    const int BT = 16 * R;
    int t = threadIdx.x;
    int tr = t >> 4, tc = t & 15;
    int c4 = (t & 15) * 4;      // float col for staging (16 threads cover 64 floats)
    int srow = t >> 4;          // staging row base (16 rows per pass)
    for (int it = 0; it < n; it += BT) {
        int ni = min(BT, n - it);
        for (int jt = 0; jt < n; jt += BT) {
            int nj = min(BT, n - jt);
            float4 acc[R][R];
#pragma unroll
            for (int ar = 0; ar < R; ++ar)
#pragma unroll
                for (int br = 0; br < R; ++br) acc[ar][br] = make_float4(0.f, 0.f, 0.f, 0.f);
            for (int d0 = 0; d0 < HWD; d0 += DT) {
                __syncthreads();
#pragma unroll
                for (int rr = 0; rr < R; ++rr) {
                    int r = srow + 16 * rr;
                    float4 vi = make_float4(0.f, 0.f, 0.f, 0.f), vj = vi;
                    if (r < ni) vi = *(const float4*)&feats[((size_t)(g0 + it + r) * CC + c) * HWD + d0 + c4];
                    if (r < nj) vj = *(const float4*)&feats[((size_t)(g0 + jt + r) * CC + c) * HWD + d0 + c4];
                    *(float4*)&Xi[r][c4] = vi;
                    *(float4*)&Xj[r][c4] = vj;
                }
                __syncthreads();
#pragma unroll
                for (int k4 = 0; k4 < DT; k4 += 4) {
                    float4 a[R], b[R];
#pragma unroll
                    for (int ar = 0; ar < R; ++ar) a[ar] = *(const float4*)&Xi[tr + 16 * ar][k4];
#pragma unroll
                    for (int br = 0; br < R; ++br) b[br] = *(const float4*)&Xj[tc + 16 * br][k4];
#pragma unroll
                    for (int ar = 0; ar < R; ++ar)
#pragma unroll
                        for (int br = 0; br < R; ++br) {
                            acc[ar][br].x += a[ar].x * b[br].x;
                            acc[ar][br].y += a[ar].y * b[br].y;
                            acc[ar][br].z += a[ar].z * b[br].z;
                            acc[ar][br].w += a[ar].w * b[br].w;
                        }
                }
            }
#pragma unroll
            for (int ar = 0; ar < R; ++ar)
#pragma unroll
                for (int br = 0; br < R; ++br) {
                    int i = it + tr + 16 * ar, j = jt + tc + 16 * br;
                    if (i < n && j < n) {
                        long p = (long)pairBase[g0 + i] + j;
                        if (p < pairCap)
                            relbuf[(size_t)p * CC + c] =
                                (acc[ar][br].x + acc[ar][br].y + acc[ar][br].z + acc[ar][br].w) * INV_NORM;
                    }
                }
        }
    }
}

__global__ void k_rel(const float* __restrict__ feats, const int* __restrict__ wsI,
                      float* __restrict__ relbuf, int pairCap) {
    __shared__ float Xi[64][DT + 4];   // 17.4 KB
    __shared__ float Xj[64][DT + 4];   // 17.4 KB  -> 34.8 KB total, 4 blocks/CU
    int m = blockIdx.x, c = blockIdx.y;
    int g0 = wsI[m], n = wsI[m + 1] - g0;
    if (n <= 0) return;
    const int* pairBase = wsI + 1088;
    if (n <= 16)      rel_impl<1>(feats, pairBase, relbuf, pairCap, c, g0, n, Xi, Xj);
    else if (n <= 32) rel_impl<2>(feats, pairBase, relbuf, pairCap, c, g0, n, Xi, Xj);
    else              rel_impl<4>(feats, pairBase, relbuf, pairCap, c, g0, n, Xi, Xj);
}

// Per-pair: add param term, softmax over 32 channels (in place)
__global__ void k_softmax(float* __restrict__ relbuf, const float* __restrict__ param,
                          const int* __restrict__ wsI, int pairCap) {
    int np = wsI[33];
    if (np > pairCap) np = pairCap;
    int p = blockIdx.x * blockDim.x + threadIdx.x;
    if (p >= np) return;
    const int* pairBase = wsI + 1088;
    int lo = 0, hi = PP - 1;   // largest i with pairBase[i] <= p
    while (lo < hi) { int mid = (lo + hi + 1) >> 1; if (pairBase[mid] <= p) lo = mid; else hi = mid - 1; }
    int i = lo;
    int j = wsI[64 + i] + (p - pairBase[i]);
    float pd = 0.f;
#pragma unroll
    for (int k = 0; k < PDIMK; ++k) pd += param[i * PDIMK + k] * param[j * PDIMK + k];
    pd *= INV_PNORM;
    float r[CC];
    float mx = -3.4e38f;
#pragma unroll
    for (int cq = 0; cq < CC; ++cq) { r[cq] = relbuf[(size_t)p * CC + cq] + pd; mx = fmaxf(mx, r[cq]); }
    float s = 0.f;
#pragma unroll
    for (int cq = 0; cq < CC; ++cq) { r[cq] = expf(r[cq] - mx); s += r[cq]; }
    float inv = 1.0f / s;
#pragma unroll
    for (int cq = 0; cq < CC; ++cq) relbuf[(size_t)p * CC + cq] = r[cq] * inv;
}

// out[i,c,d] = relu( sum_j att[c,i,j] * x[c,j,d] + x[c,i,d] )
// Grid: (image, channel, d-chunk of 256). jj/ii chunked by 32. For n<=32 this
// is a single-pass fast path; n>32 accumulates through out[] inside one block
// (sequential within the block -> deterministic).
__global__ __launch_bounds__(256) void k_out(const float* __restrict__ feats,
                                             const float* __restrict__ att,
                                             const int* __restrict__ wsI,
                                             float* __restrict__ out, int pairCap) {
    __shared__ float Xs[32][258];      // 33.0 KB
    __shared__ float att_s[32][32];    // 4.0 KB  -> 37.1 KB total, 4 blocks/CU
    int m = blockIdx.x, c = blockIdx.y;
    int d0 = blockIdx.z * 256;
    int g0 = wsI[m], n = wsI[m + 1] - g0;
    if (n <= 0) return;
    const int* pairBase = wsI + 1088;
    int t = threadIdx.x;
    int f4 = (t & 63) * 4;
    for (int jc = 0; jc < n; jc += 32) {
        int nj = min(32, n - jc);
        __syncthreads();   // previous compute done reading Xs
        for (int r = t >> 6; r < nj; r += 4)
            *(float4*)&Xs[r][f4] = *(const float4*)&feats[((size_t)(g0 + jc + r) * CC + c) * HWD + d0 + f4];
        bool first = (jc == 0), last = (jc + 32 >= n);
        for (int ic = 0; ic < n; ic += 32) {
            int ni = min(32, n - ic);
            __syncthreads();   // previous compute done reading att_s
            for (int idx = t; idx < 1024; idx += 256) {
                int ii = idx >> 5, jj = idx & 31;
                float a = 0.f;
                if (ii < ni && jj < nj) {
                    long p = (long)pairBase[g0 + ic + ii] + jc + jj;
                    if (p < pairCap) a = att[(size_t)p * CC + c];
                }
                att_s[ii][jj] = a;
            }
            __syncthreads();   // Xs + att_s ready
            for (int ii = 0; ii < ni; ++ii) {
                float acc0 = 0.f, acc1 = 0.f;
                int jj = 0;
                for (; jj + 1 < nj; jj += 2) {
                    acc0 += att_s[ii][jj]     * Xs[jj][t];
                    acc1 += att_s[ii][jj + 1] * Xs[jj + 1][t];
                }
                if (jj < nj) acc0 += att_s[ii][jj] * Xs[jj][t];
                float acc = acc0 + acc1;
                size_t o = ((size_t)(g0 + ic + ii) * CC + c) * HWD + d0 + t;
                if (first) {
                    if (last) out[o] = fmaxf(acc + Xs[ii][t], 0.f);   // n<=32: ii is in Xs
                    else      out[o] = acc;
                } else {
                    float v = out[o] + acc;
                    if (last) out[o] = fmaxf(v + feats[o], 0.f);
                    else      out[o] = v;
                }
            }
        }
    }
}

extern "C" void kernel_launch(void* const* d_in, const int* in_sizes, int n_in,
                              void* d_out, int out_size, void* d_ws, size_t ws_size,
                              hipStream_t stream) {
    const float* feats = (const float*)d_in[0];
    const int*   imgid = (const int*)d_in[1];
    const float* param = (const float*)d_in[2];
    float* out = (float*)d_out;
    int* wsI = (int*)d_ws;
    float* relbuf = (float*)((char*)d_ws + 8192);

    long pairCapL = ((long)ws_size - 8192) / (CC * 4);
    if (pairCapL < 0) pairCapL = 0;
    if (pairCapL > (long)PP * PP) pairCapL = (long)PP * PP;
    int pairCap = (int)pairCapL;

    k_groups<<<1, PP, 0, stream>>>(imgid, wsI);
    k_rel<<<dim3(NIMG, CC), 256, 0, stream>>>(feats, wsI, relbuf, pairCap);
    k_softmax<<<dim3((PP * PP + 255) / 256), 256, 0, stream>>>(relbuf, param, wsI, pairCap);
    k_out<<<dim3(NIMG, CC, HWD / 256), 256, 0, stream>>>(feats, relbuf, wsI, out, pairCap);
}

// Round 3
// 320.951 us; speedup vs baseline: 4.3073x; 1.4479x over previous
//
#include <hip/hip_runtime.h>

#define PP   512
#define CC   32
#define HWD  3072           // 64*48
#define PDIMK 34
#define NIMG 32
#define DTR  128            // k_rel d-chunk

static constexpr float INV_NORM  = 1.0f / 96.0f;
static constexpr float INV_PNORM = 1.0f / 480.0f;

// workspace int layout:
// [0..32]      gstart (33)
// [33]         npairs
// [64..575]    start[i]
// [576..1087]  cnt[i]
// [1088..1599] pairBase[i]  (exclusive prefix sum of cnt)
// byte 8192+:  rel/att buffer, TRANSPOSED layout [c][strideP] floats

__global__ void k_groups(const int* __restrict__ imgid, int* __restrict__ wsI) {
    __shared__ int s_img[PP];
    __shared__ int s_cnt[PP];
    int t = threadIdx.x;
    s_img[t] = imgid[t];
    __syncthreads();
    int v = s_img[t];
    int lo = 0, hi = PP;
    while (lo < hi) { int mid = (lo + hi) >> 1; if (s_img[mid] < v) lo = mid + 1; else hi = mid; }
    int st = lo;
    lo = 0; hi = PP;
    while (lo < hi) { int mid = (lo + hi) >> 1; if (s_img[mid] <= v) lo = mid + 1; else hi = mid; }
    int cn = lo - st;
    wsI[64 + t]  = st;
    wsI[576 + t] = cn;
    s_cnt[t] = cn;
    if (t <= NIMG) {
        lo = 0; hi = PP;
        while (lo < hi) { int mid = (lo + hi) >> 1; if (s_img[mid] < t) lo = mid + 1; else hi = mid; }
        wsI[t] = lo;
    }
    __syncthreads();
    if (t == 0) {
        int acc = 0;
        for (int i = 0; i < PP; ++i) { wsI[1088 + i] = acc; acc += s_cnt[i]; }
        wsI[33] = acc;
    }
}

// rel[c][p(i,j)] = dot(x[c,i,:], x[c,j,:]) / 96   (transposed layout)
__global__ __launch_bounds__(256) void k_rel(const float* __restrict__ feats,
                                             const int* __restrict__ wsI,
                                             float* __restrict__ relbuf, int strideP) {
    __shared__ float X[32][DTR + 4];    // 16.9 KB
    int m = blockIdx.x, c = blockIdx.y;
    int g0 = wsI[m], n = wsI[m + 1] - g0;
    if (n <= 0) return;
    const int* pairBase = wsI + 1088;
    int t = threadIdx.x;
    int sr = t >> 5, sc = (t & 31) * 4;     // staging: 8 rows x 128 cols per pass

    if (n <= 16) {
        int i = t >> 4, j = t & 15;
        float4 a4 = make_float4(0.f, 0.f, 0.f, 0.f);
        for (int d0 = 0; d0 < HWD; d0 += DTR) {
            __syncthreads();
            if (sr < n)     *(float4*)&X[sr][sc]     = *(const float4*)&feats[((size_t)(g0 + sr) * CC + c) * HWD + d0 + sc];
            if (sr + 8 < n) *(float4*)&X[sr + 8][sc] = *(const float4*)&feats[((size_t)(g0 + sr + 8) * CC + c) * HWD + d0 + sc];
            __syncthreads();
#pragma unroll
            for (int k = 0; k < DTR; k += 4) {
                float4 xi = *(const float4*)&X[i][k];
                float4 xj = *(const float4*)&X[j][k];
                a4.x += xi.x * xj.x; a4.y += xi.y * xj.y;
                a4.z += xi.z * xj.z; a4.w += xi.w * xj.w;
            }
        }
        if (i < n && j < n) {
            int p = pairBase[g0 + i] + j;
            if (p < strideP) relbuf[(size_t)c * strideP + p] = (a4.x + a4.y + a4.z + a4.w) * INV_NORM;
        }
    } else if (n <= 32) {
        // 2x2 pairs per thread via offset-16 tiling: (i, i+16) x (j, j+16)
        int i0 = t >> 4, j0 = t & 15;
        float4 a00 = make_float4(0,0,0,0), a01 = a00, a10 = a00, a11 = a00;
        for (int d0 = 0; d0 < HWD; d0 += DTR) {
            __syncthreads();
#pragma unroll
            for (int rr = 0; rr < 4; ++rr) {
                int r = sr + rr * 8;
                if (r < n) *(float4*)&X[r][sc] = *(const float4*)&feats[((size_t)(g0 + r) * CC + c) * HWD + d0 + sc];
            }
            __syncthreads();
#pragma unroll
            for (int k = 0; k < DTR; k += 4) {
                float4 xi0 = *(const float4*)&X[i0][k];
                float4 xi1 = *(const float4*)&X[i0 + 16][k];
                float4 xj0 = *(const float4*)&X[j0][k];
                float4 xj1 = *(const float4*)&X[j0 + 16][k];
                a00.x += xi0.x * xj0.x; a00.y += xi0.y * xj0.y; a00.z += xi0.z * xj0.z; a00.w += xi0.w * xj0.w;
                a01.x += xi0.x * xj1.x; a01.y += xi0.y * xj1.y; a01.z += xi0.z * xj1.z; a01.w += xi0.w * xj1.w;
                a10.x += xi1.x * xj0.x; a10.y += xi1.y * xj0.y; a10.z += xi1.z * xj0.z; a10.w += xi1.w * xj0.w;
                a11.x += xi1.x * xj1.x; a11.y += xi1.y * xj1.y; a11.z += xi1.z * xj1.z; a11.w += xi1.w * xj1.w;
            }
        }
        float r00 = (a00.x + a00.y + a00.z + a00.w) * INV_NORM;
        float r01 = (a01.x + a01.y + a01.z + a01.w) * INV_NORM;
        float r10 = (a10.x + a10.y + a10.z + a10.w) * INV_NORM;
        float r11 = (a11.x + a11.y + a11.z + a11.w) * INV_NORM;
        if (j0 < n) {
            if (i0 < n)      { int p = pairBase[g0 + i0] + j0;      if (p < strideP) relbuf[(size_t)c * strideP + p] = r00; }
            if (i0 + 16 < n) { int p = pairBase[g0 + i0 + 16] + j0; if (p < strideP) relbuf[(size_t)c * strideP + p] = r10; }
        }
        if (j0 + 16 < n) {
            if (i0 < n)      { int p = pairBase[g0 + i0] + j0 + 16;      if (p < strideP) relbuf[(size_t)c * strideP + p] = r01; }
            if (i0 + 16 < n) { int p = pairBase[g0 + i0 + 16] + j0 + 16; if (p < strideP) relbuf[(size_t)c * strideP + p] = r11; }
        }
    } else {
        // generic fallback (statistically unreachable): 16x16 tile pairs
        for (int it = 0; it < n; it += 16)
            for (int jt = 0; jt < n; jt += 16) {
                int i = it + (t >> 4), j = jt + (t & 15);
                float4 a4 = make_float4(0,0,0,0);
                for (int d0 = 0; d0 < HWD; d0 += DTR) {
                    __syncthreads();
                    if (sr < 16 && it + sr < n)
                        *(float4*)&X[sr][sc] = *(const float4*)&feats[((size_t)(g0 + it + sr) * CC + c) * HWD + d0 + sc];
                    if (it + sr + 8 < n)
                        *(float4*)&X[sr + 8][sc] = *(const float4*)&feats[((size_t)(g0 + it + sr + 8) * CC + c) * HWD + d0 + sc];
                    if (jt + sr < n)
                        *(float4*)&X[16 + sr][sc] = *(const float4*)&feats[((size_t)(g0 + jt + sr) * CC + c) * HWD + d0 + sc];
                    if (jt + sr + 8 < n)
                        *(float4*)&X[24 + sr][sc] = *(const float4*)&feats[((size_t)(g0 + jt + sr + 8) * CC + c) * HWD + d0 + sc];
                    __syncthreads();
#pragma unroll
                    for (int k = 0; k < DTR; k += 4) {
                        float4 xi = *(const float4*)&X[t >> 4][k];
                        float4 xj = *(const float4*)&X[16 + (t & 15)][k];
                        a4.x += xi.x * xj.x; a4.y += xi.y * xj.y;
                        a4.z += xi.z * xj.z; a4.w += xi.w * xj.w;
                    }
                }
                if (i < n && j < n) {
                    int p = pairBase[g0 + i] + j;
                    if (p < strideP) relbuf[(size_t)c * strideP + p] = (a4.x + a4.y + a4.z + a4.w) * INV_NORM;
                }
            }
    }
}

// softmax over channels, tiled transpose for coalescing; adds param term
__global__ __launch_bounds__(256) void k_softmax(float* __restrict__ relbuf,
                                                 const float* __restrict__ param,
                                                 const int* __restrict__ wsI, int strideP) {
    int np = wsI[33];
    if (np > strideP) np = strideP;
    int p0 = blockIdx.x * 64;
    if (p0 >= np) return;
    int nv = min(64, np - p0);
    __shared__ float tile[CC][68];   // 8.7 KB
    int t = threadIdx.x;
    for (int idx = t; idx < CC * 16; idx += 256) {
        int c = idx >> 4, q4 = (idx & 15) * 4;
        if (q4 + 4 <= nv) {
            *(float4*)&tile[c][q4] = *(const float4*)&relbuf[(size_t)c * strideP + p0 + q4];
        } else {
#pragma unroll
            for (int e = 0; e < 4; ++e)
                if (q4 + e < nv) tile[c][q4 + e] = relbuf[(size_t)c * strideP + p0 + q4 + e];
        }
    }
    __syncthreads();
    if (t < 64 && t < nv) {
        int p = p0 + t;
        const int* pairBase = wsI + 1088;
        int lo = 0, hi = PP - 1;
        while (lo < hi) { int mid = (lo + hi + 1) >> 1; if (pairBase[mid] <= p) lo = mid; else hi = mid - 1; }
        int i = lo;
        int j = wsI[64 + i] + (p - pairBase[i]);
        float pd = 0.f;
#pragma unroll
        for (int k = 0; k < PDIMK; ++k) pd += param[i * PDIMK + k] * param[j * PDIMK + k];
        pd *= INV_PNORM;
        float mx = -3.4e38f;
#pragma unroll
        for (int c = 0; c < CC; ++c) mx = fmaxf(mx, tile[c][t] + pd);
        float s = 0.f;
#pragma unroll
        for (int c = 0; c < CC; ++c) { float e = __expf(tile[c][t] + pd - mx); tile[c][t] = e; s += e; }
        float inv = 1.0f / s;
#pragma unroll
        for (int c = 0; c < CC; ++c) tile[c][t] *= inv;
    }
    __syncthreads();
    for (int idx = t; idx < CC * 16; idx += 256) {
        int c = idx >> 4, q4 = (idx & 15) * 4;
        if (q4 + 4 <= nv) {
            *(float4*)&relbuf[(size_t)c * strideP + p0 + q4] = *(const float4*)&tile[c][q4];
        } else {
#pragma unroll
            for (int e = 0; e < 4; ++e)
                if (q4 + e < nv) relbuf[(size_t)c * strideP + p0 + q4 + e] = tile[c][q4 + e];
        }
    }
}

// out[i,c,d] = relu( sum_j (att[c,i,j] + delta_ij) * x[j,c,d] )
// Block (m, c, d-chunk of 1024). Thread owns 4 cols (float4); acc for all NT
// rows in registers (static unroll). Two tiers: NT=16 (n<=16), NT=32 (n>16).
template<int NT>
__global__ __launch_bounds__(256) void k_out_t(const float* __restrict__ feats,
                                               const float* __restrict__ att,
                                               const int* __restrict__ wsI,
                                               float* __restrict__ out, int strideP) {
    int m = blockIdx.x, c = blockIdx.y;
    int g0 = wsI[m], n = wsI[m + 1] - g0;
    if (n <= 0) return;
    if (NT == 16) { if (n > 16) return; }
    else          { if (n <= 16) return; }
    __shared__ float att_t[32][NT + 4];
    const int* pairBase = wsI + 1088;
    int t = threadIdx.x;
    int col = blockIdx.z * 1024 + t * 4;

    for (int ic = 0; ic < n; ic += NT) {
        int ni = min(NT, n - ic);
        float4 acc[NT];
#pragma unroll
        for (int q = 0; q < NT; ++q) acc[q] = make_float4(0.f, 0.f, 0.f, 0.f);
        for (int jc = 0; jc < n; jc += 32) {
            int nj = min(32, n - jc);
            __syncthreads();
            for (int idx = t; idx < 32 * NT; idx += 256) {
                int jj = idx & 31, ii = idx >> 5;
                float a = 0.f;
                if (ii < ni && jj < nj) {
                    int p = pairBase[g0 + ic + ii] + jc + jj;
                    if (p < strideP) a = att[(size_t)c * strideP + p];
                    if (ic + ii == jc + jj) a += 1.0f;   // residual folded in
                }
                att_t[jj][ii] = a;
            }
            __syncthreads();
            for (int jj = 0; jj < nj; ++jj) {
                float4 vj = *(const float4*)&feats[((size_t)(g0 + jc + jj) * CC + c) * HWD + col];
#pragma unroll
                for (int q = 0; q < NT / 4; ++q) {
                    float4 a4 = *(const float4*)&att_t[jj][q * 4];
                    acc[q * 4 + 0].x += a4.x * vj.x; acc[q * 4 + 0].y += a4.x * vj.y;
                    acc[q * 4 + 0].z += a4.x * vj.z; acc[q * 4 + 0].w += a4.x * vj.w;
                    acc[q * 4 + 1].x += a4.y * vj.x; acc[q * 4 + 1].y += a4.y * vj.y;
                    acc[q * 4 + 1].z += a4.y * vj.z; acc[q * 4 + 1].w += a4.y * vj.w;
                    acc[q * 4 + 2].x += a4.z * vj.x; acc[q * 4 + 2].y += a4.z * vj.y;
                    acc[q * 4 + 2].z += a4.z * vj.z; acc[q * 4 + 2].w += a4.z * vj.w;
                    acc[q * 4 + 3].x += a4.w * vj.x; acc[q * 4 + 3].y += a4.w * vj.y;
                    acc[q * 4 + 3].z += a4.w * vj.z; acc[q * 4 + 3].w += a4.w * vj.w;
                }
            }
        }
#pragma unroll
        for (int ii = 0; ii < NT; ++ii) {
            if (ii < ni) {
                float4 r = acc[ii];
                r.x = fmaxf(r.x, 0.f); r.y = fmaxf(r.y, 0.f);
                r.z = fmaxf(r.z, 0.f); r.w = fmaxf(r.w, 0.f);
                *(float4*)&out[((size_t)(g0 + ic + ii) * CC + c) * HWD + col] = r;
            }
        }
    }
}

extern "C" void kernel_launch(void* const* d_in, const int* in_sizes, int n_in,
                              void* d_out, int out_size, void* d_ws, size_t ws_size,
                              hipStream_t stream) {
    const float* feats = (const float*)d_in[0];
    const int*   imgid = (const int*)d_in[1];
    const float* param = (const float*)d_in[2];
    float* out = (float*)d_out;
    int* wsI = (int*)d_ws;
    float* relbuf = (float*)((char*)d_ws + 8192);

    long capL = ((long)ws_size - 8192) / (CC * 4);
    if (capL < 0) capL = 0;
    if (capL > (long)PP * PP) capL = (long)PP * PP;
    int strideP = (int)capL;

    k_groups<<<1, PP, 0, stream>>>(imgid, wsI);
    k_rel<<<dim3(NIMG, CC), 256, 0, stream>>>(feats, wsI, relbuf, strideP);
    k_softmax<<<dim3((PP * PP + 63) / 64), 256, 0, stream>>>(relbuf, param, wsI, strideP);
    k_out_t<16><<<dim3(NIMG, CC, 3), 256, 0, stream>>>(feats, relbuf, wsI, out, strideP);
    k_out_t<32><<<dim3(NIMG, CC, 3), 256, 0, stream>>>(feats, relbuf, wsI, out, strideP);
}

// Round 4
// 240.035 us; speedup vs baseline: 5.7593x; 1.3371x over previous
//
#include <hip/hip_runtime.h>

#define PP   512
#define CC   32
#define HWD  3072           // 64*48
#define PDIMK 34
#define NIMG 32
#define DTR  128            // k_rel d-chunk

static constexpr float INV_NORM  = 1.0f / 96.0f;
static constexpr float INV_PNORM = 1.0f / 480.0f;

// workspace int layout:
// [0..32]      gstart (33)
// [33]         npairs
// [64..575]    start[i]
// [576..1087]  cnt[i]
// [1088..1599] pairBase[i]  (exclusive prefix sum of cnt)
// byte 8192+:  rel/att buffer, TRANSPOSED layout [c][strideP] floats

__global__ void k_groups(const int* __restrict__ imgid, int* __restrict__ wsI) {
    __shared__ int s_img[PP];
    __shared__ int s_cnt[PP];
    int t = threadIdx.x;
    s_img[t] = imgid[t];
    __syncthreads();
    int v = s_img[t];
    int lo = 0, hi = PP;
    while (lo < hi) { int mid = (lo + hi) >> 1; if (s_img[mid] < v) lo = mid + 1; else hi = mid; }
    int st = lo;
    lo = 0; hi = PP;
    while (lo < hi) { int mid = (lo + hi) >> 1; if (s_img[mid] <= v) lo = mid + 1; else hi = mid; }
    int cn = lo - st;
    wsI[64 + t]  = st;
    wsI[576 + t] = cn;
    s_cnt[t] = cn;
    if (t <= NIMG) {
        lo = 0; hi = PP;
        while (lo < hi) { int mid = (lo + hi) >> 1; if (s_img[mid] < t) lo = mid + 1; else hi = mid; }
        wsI[t] = lo;
    }
    __syncthreads();
    if (t == 0) {
        int acc = 0;
        for (int i = 0; i < PP; ++i) { wsI[1088 + i] = acc; acc += s_cnt[i]; }
        wsI[33] = acc;
    }
}

// rel[c][p(i,j)] = dot(x[c,i,:], x[c,j,:]) / 96   (transposed layout)
__global__ __launch_bounds__(256) void k_rel(const float* __restrict__ feats,
                                             const int* __restrict__ wsI,
                                             float* __restrict__ relbuf, int strideP) {
    __shared__ float X[32][DTR + 4];    // 16.9 KB
    int m = blockIdx.x, c = blockIdx.y;
    int g0 = wsI[m], n = wsI[m + 1] - g0;
    if (n <= 0) return;
    const int* pairBase = wsI + 1088;
    int t = threadIdx.x;
    int sr = t >> 5, sc = (t & 31) * 4;     // staging: 8 rows x 128 cols per pass

    if (n <= 16) {
        int i = t >> 4, j = t & 15;
        float4 a4 = make_float4(0.f, 0.f, 0.f, 0.f);
        for (int d0 = 0; d0 < HWD; d0 += DTR) {
            __syncthreads();
            if (sr < n)     *(float4*)&X[sr][sc]     = *(const float4*)&feats[((size_t)(g0 + sr) * CC + c) * HWD + d0 + sc];
            if (sr + 8 < n) *(float4*)&X[sr + 8][sc] = *(const float4*)&feats[((size_t)(g0 + sr + 8) * CC + c) * HWD + d0 + sc];
            __syncthreads();
#pragma unroll
            for (int k = 0; k < DTR; k += 4) {
                float4 xi = *(const float4*)&X[i][k];
                float4 xj = *(const float4*)&X[j][k];
                a4.x += xi.x * xj.x; a4.y += xi.y * xj.y;
                a4.z += xi.z * xj.z; a4.w += xi.w * xj.w;
            }
        }
        if (i < n && j < n) {
            int p = pairBase[g0 + i] + j;
            if (p < strideP) relbuf[(size_t)c * strideP + p] = (a4.x + a4.y + a4.z + a4.w) * INV_NORM;
        }
    } else if (n <= 32) {
        // 2x2 pairs per thread via offset-16 tiling: (i, i+16) x (j, j+16)
        int i0 = t >> 4, j0 = t & 15;
        float4 a00 = make_float4(0,0,0,0), a01 = a00, a10 = a00, a11 = a00;
        for (int d0 = 0; d0 < HWD; d0 += DTR) {
            __syncthreads();
#pragma unroll
            for (int rr = 0; rr < 4; ++rr) {
                int r = sr + rr * 8;
                if (r < n) *(float4*)&X[r][sc] = *(const float4*)&feats[((size_t)(g0 + r) * CC + c) * HWD + d0 + sc];
            }
            __syncthreads();
#pragma unroll
            for (int k = 0; k < DTR; k += 4) {
                float4 xi0 = *(const float4*)&X[i0][k];
                float4 xi1 = *(const float4*)&X[i0 + 16][k];
                float4 xj0 = *(const float4*)&X[j0][k];
                float4 xj1 = *(const float4*)&X[j0 + 16][k];
                a00.x += xi0.x * xj0.x; a00.y += xi0.y * xj0.y; a00.z += xi0.z * xj0.z; a00.w += xi0.w * xj0.w;
                a01.x += xi0.x * xj1.x; a01.y += xi0.y * xj1.y; a01.z += xi0.z * xj1.z; a01.w += xi0.w * xj1.w;
                a10.x += xi1.x * xj0.x; a10.y += xi1.y * xj0.y; a10.z += xi1.z * xj0.z; a10.w += xi1.w * xj0.w;
                a11.x += xi1.x * xj1.x; a11.y += xi1.y * xj1.y; a11.z += xi1.z * xj1.z; a11.w += xi1.w * xj1.w;
            }
        }
        float r00 = (a00.x + a00.y + a00.z + a00.w) * INV_NORM;
        float r01 = (a01.x + a01.y + a01.z + a01.w) * INV_NORM;
        float r10 = (a10.x + a10.y + a10.z + a10.w) * INV_NORM;
        float r11 = (a11.x + a11.y + a11.z + a11.w) * INV_NORM;
        if (j0 < n) {
            if (i0 < n)      { int p = pairBase[g0 + i0] + j0;      if (p < strideP) relbuf[(size_t)c * strideP + p] = r00; }
            if (i0 + 16 < n) { int p = pairBase[g0 + i0 + 16] + j0; if (p < strideP) relbuf[(size_t)c * strideP + p] = r10; }
        }
        if (j0 + 16 < n) {
            if (i0 < n)      { int p = pairBase[g0 + i0] + j0 + 16;      if (p < strideP) relbuf[(size_t)c * strideP + p] = r01; }
            if (i0 + 16 < n) { int p = pairBase[g0 + i0 + 16] + j0 + 16; if (p < strideP) relbuf[(size_t)c * strideP + p] = r11; }
        }
    } else {
        // generic fallback (statistically unreachable): 16x16 tile pairs
        for (int it = 0; it < n; it += 16)
            for (int jt = 0; jt < n; jt += 16) {
                int i = it + (t >> 4), j = jt + (t & 15);
                float4 a4 = make_float4(0,0,0,0);
                for (int d0 = 0; d0 < HWD; d0 += DTR) {
                    __syncthreads();
                    if (sr < 16 && it + sr < n)
                        *(float4*)&X[sr][sc] = *(const float4*)&feats[((size_t)(g0 + it + sr) * CC + c) * HWD + d0 + sc];
                    if (it + sr + 8 < n)
                        *(float4*)&X[sr + 8][sc] = *(const float4*)&feats[((size_t)(g0 + it + sr + 8) * CC + c) * HWD + d0 + sc];
                    if (jt + sr < n)
                        *(float4*)&X[16 + sr][sc] = *(const float4*)&feats[((size_t)(g0 + jt + sr) * CC + c) * HWD + d0 + sc];
                    if (jt + sr + 8 < n)
                        *(float4*)&X[24 + sr][sc] = *(const float4*)&feats[((size_t)(g0 + jt + sr + 8) * CC + c) * HWD + d0 + sc];
                    __syncthreads();
#pragma unroll
                    for (int k = 0; k < DTR; k += 4) {
                        float4 xi = *(const float4*)&X[t >> 4][k];
                        float4 xj = *(const float4*)&X[16 + (t & 15)][k];
                        a4.x += xi.x * xj.x; a4.y += xi.y * xj.y;
                        a4.z += xi.z * xj.z; a4.w += xi.w * xj.w;
                    }
                }
                if (i < n && j < n) {
                    int p = pairBase[g0 + i] + j;
                    if (p < strideP) relbuf[(size_t)c * strideP + p] = (a4.x + a4.y + a4.z + a4.w) * INV_NORM;
                }
            }
    }
}

// softmax over channels, tiled transpose for coalescing; adds param term
__global__ __launch_bounds__(256) void k_softmax(float* __restrict__ relbuf,
                                                 const float* __restrict__ param,
                                                 const int* __restrict__ wsI, int strideP) {
    int np = wsI[33];
    if (np > strideP) np = strideP;
    int p0 = blockIdx.x * 64;
    if (p0 >= np) return;
    int nv = min(64, np - p0);
    __shared__ float tile[CC][68];   // 8.7 KB
    int t = threadIdx.x;
    for (int idx = t; idx < CC * 16; idx += 256) {
        int c = idx >> 4, q4 = (idx & 15) * 4;
        if (q4 + 4 <= nv) {
            *(float4*)&tile[c][q4] = *(const float4*)&relbuf[(size_t)c * strideP + p0 + q4];
        } else {
#pragma unroll
            for (int e = 0; e < 4; ++e)
                if (q4 + e < nv) tile[c][q4 + e] = relbuf[(size_t)c * strideP + p0 + q4 + e];
        }
    }
    __syncthreads();
    if (t < 64 && t < nv) {
        int p = p0 + t;
        const int* pairBase = wsI + 1088;
        int lo = 0, hi = PP - 1;
        while (lo < hi) { int mid = (lo + hi + 1) >> 1; if (pairBase[mid] <= p) lo = mid; else hi = mid - 1; }
        int i = lo;
        int j = wsI[64 + i] + (p - pairBase[i]);
        float pd = 0.f;
#pragma unroll
        for (int k = 0; k < PDIMK; ++k) pd += param[i * PDIMK + k] * param[j * PDIMK + k];
        pd *= INV_PNORM;
        float mx = -3.4e38f;
#pragma unroll
        for (int c = 0; c < CC; ++c) mx = fmaxf(mx, tile[c][t] + pd);
        float s = 0.f;
#pragma unroll
        for (int c = 0; c < CC; ++c) { float e = __expf(tile[c][t] + pd - mx); tile[c][t] = e; s += e; }
        float inv = 1.0f / s;
#pragma unroll
        for (int c = 0; c < CC; ++c) tile[c][t] *= inv;
    }
    __syncthreads();
    for (int idx = t; idx < CC * 16; idx += 256) {
        int c = idx >> 4, q4 = (idx & 15) * 4;
        if (q4 + 4 <= nv) {
            *(float4*)&relbuf[(size_t)c * strideP + p0 + q4] = *(const float4*)&tile[c][q4];
        } else {
#pragma unroll
            for (int e = 0; e < 4; ++e)
                if (q4 + e < nv) relbuf[(size_t)c * strideP + p0 + q4 + e] = tile[c][q4 + e];
        }
    }
}

// out[i,c,d] = relu( sum_j (att[c,i,j] + delta_ij) * x[j,c,d] )
// Single merged kernel: block (m, c, d-chunk of 1024), thread owns 4 cols.
// ic chunks of 16 (acc[16] float4 in regs, static), jc chunks of 32.
// n<=16: single pass. 17..32: 2 ic passes (j-rows re-read from L2/L3).
__global__ __launch_bounds__(256) void k_out(const float* __restrict__ feats,
                                             const float* __restrict__ att,
                                             const int* __restrict__ wsI,
                                             float* __restrict__ out, int strideP) {
    __shared__ float att_t[32][20];    // [jj][ii], 2.5 KB
    int m = blockIdx.x, c = blockIdx.y;
    int g0 = wsI[m], n = wsI[m + 1] - g0;
    if (n <= 0) return;
    const int* pairBase = wsI + 1088;
    int t = threadIdx.x;
    int col = blockIdx.z * 1024 + t * 4;
    const size_t rs = (size_t)CC * HWD;                     // row stride (floats)
    const float* fb = feats + ((size_t)g0 * CC + c) * HWD + col;
    float*       ob = out   + ((size_t)g0 * CC + c) * HWD + col;

    for (int ic = 0; ic < n; ic += 16) {
        int ni = min(16, n - ic);
        float4 acc[16];
#pragma unroll
        for (int q = 0; q < 16; ++q) acc[q] = make_float4(0.f, 0.f, 0.f, 0.f);
        for (int jc = 0; jc < n; jc += 32) {
            int nj = min(32, n - jc);
            __syncthreads();
            for (int idx = t; idx < 512; idx += 256) {      // 32 jj x 16 ii
                int jj = idx & 31, ii = idx >> 5;
                float a = 0.f;
                if (ii < ni && jj < nj) {
                    int p = pairBase[g0 + ic + ii] + jc + jj;
                    if (p < strideP) a = att[(size_t)c * strideP + p];
                    if (ic + ii == jc + jj) a += 1.0f;      // residual folded in
                }
                att_t[jj][ii] = a;
            }
            __syncthreads();
            const float* fj = fb + (size_t)jc * rs;
            float4 vnext = *(const float4*)fj;              // nj >= 1 always here
            for (int jj = 0; jj < nj; ++jj) {
                float4 vj = vnext;
                if (jj + 1 < nj) vnext = *(const float4*)(fj + (size_t)(jj + 1) * rs);
                float4 a0 = *(const float4*)&att_t[jj][0];   // broadcast reads
                float4 a1 = *(const float4*)&att_t[jj][4];
                float4 a2 = *(const float4*)&att_t[jj][8];
                float4 a3 = *(const float4*)&att_t[jj][12];
                acc[0].x  += a0.x * vj.x; acc[0].y  += a0.x * vj.y; acc[0].z  += a0.x * vj.z; acc[0].w  += a0.x * vj.w;
                acc[1].x  += a0.y * vj.x; acc[1].y  += a0.y * vj.y; acc[1].z  += a0.y * vj.z; acc[1].w  += a0.y * vj.w;
                acc[2].x  += a0.z * vj.x; acc[2].y  += a0.z * vj.y; acc[2].z  += a0.z * vj.z; acc[2].w  += a0.z * vj.w;
                acc[3].x  += a0.w * vj.x; acc[3].y  += a0.w * vj.y; acc[3].z  += a0.w * vj.z; acc[3].w  += a0.w * vj.w;
                acc[4].x  += a1.x * vj.x; acc[4].y  += a1.x * vj.y; acc[4].z  += a1.x * vj.z; acc[4].w  += a1.x * vj.w;
                acc[5].x  += a1.y * vj.x; acc[5].y  += a1.y * vj.y; acc[5].z  += a1.y * vj.z; acc[5].w  += a1.y * vj.w;
                acc[6].x  += a1.z * vj.x; acc[6].y  += a1.z * vj.y; acc[6].z  += a1.z * vj.z; acc[6].w  += a1.z * vj.w;
                acc[7].x  += a1.w * vj.x; acc[7].y  += a1.w * vj.y; acc[7].z  += a1.w * vj.z; acc[7].w  += a1.w * vj.w;
                acc[8].x  += a2.x * vj.x; acc[8].y  += a2.x * vj.y; acc[8].z  += a2.x * vj.z; acc[8].w  += a2.x * vj.w;
                acc[9].x  += a2.y * vj.x; acc[9].y  += a2.y * vj.y; acc[9].z  += a2.y * vj.z; acc[9].w  += a2.y * vj.w;
                acc[10].x += a2.z * vj.x; acc[10].y += a2.z * vj.y; acc[10].z += a2.z * vj.z; acc[10].w += a2.z * vj.w;
                acc[11].x += a2.w * vj.x; acc[11].y += a2.w * vj.y; acc[11].z += a2.w * vj.z; acc[11].w += a2.w * vj.w;
                acc[12].x += a3.x * vj.x; acc[12].y += a3.x * vj.y; acc[12].z += a3.x * vj.z; acc[12].w += a3.x * vj.w;
                acc[13].x += a3.y * vj.x; acc[13].y += a3.y * vj.y; acc[13].z += a3.y * vj.z; acc[13].w += a3.y * vj.w;
                acc[14].x += a3.z * vj.x; acc[14].y += a3.z * vj.y; acc[14].z += a3.z * vj.z; acc[14].w += a3.z * vj.w;
                acc[15].x += a3.w * vj.x; acc[15].y += a3.w * vj.y; acc[15].z += a3.w * vj.z; acc[15].w += a3.w * vj.w;
            }
        }
#pragma unroll
        for (int ii = 0; ii < 16; ++ii) {
            if (ii < ni) {
                float4 r = acc[ii];
                r.x = fmaxf(r.x, 0.f); r.y = fmaxf(r.y, 0.f);
                r.z = fmaxf(r.z, 0.f); r.w = fmaxf(r.w, 0.f);
                *(float4*)&ob[(size_t)(ic + ii) * rs] = r;
            }
        }
    }
}

extern "C" void kernel_launch(void* const* d_in, const int* in_sizes, int n_in,
                              void* d_out, int out_size, void* d_ws, size_t ws_size,
                              hipStream_t stream) {
    const float* feats = (const float*)d_in[0];
    const int*   imgid = (const int*)d_in[1];
    const float* param = (const float*)d_in[2];
    float* out = (float*)d_out;
    int* wsI = (int*)d_ws;
    float* relbuf = (float*)((char*)d_ws + 8192);

    long capL = ((long)ws_size - 8192) / (CC * 4);
    if (capL < 0) capL = 0;
    if (capL > (long)PP * PP) capL = (long)PP * PP;
    int strideP = (int)capL;

    k_groups<<<1, PP, 0, stream>>>(imgid, wsI);
    k_rel<<<dim3(NIMG, CC), 256, 0, stream>>>(feats, wsI, relbuf, strideP);
    k_softmax<<<dim3((PP * PP + 63) / 64), 256, 0, stream>>>(relbuf, param, wsI, strideP);
    k_out<<<dim3(NIMG, CC, 3), 256, 0, stream>>>(feats, relbuf, wsI, out, strideP);
}